// Round 7
// baseline (503736.768 us; speedup 1.0000x reference)
//
#include <hip/hip_runtime.h>
#include <math.h>

// Problem constants: B=64, S=512, IN=300, H=512, NT=9, NC=2

struct StepParams {
  const float* x;
  const float* Wih_f; const float* Whh_f; const float* bih_f; const float* bhh_f;
  const float* Wih_r; const float* Whh_r; const float* bih_r; const float* bhh_r;
  const float* h_src; float* h_dst; float* c_buf; float* outcat; float* h_red;
  const int* lengths; int t;
};

// ---------------------------------------------------------------------------
// prep: lengths, CRF valid-index compaction, zero h_a/h_b/c/accums
// ---------------------------------------------------------------------------
__global__ void __launch_bounds__(64) prep_kernel(const int* amask, const int* tok_labels,
                                                  int* lengths, int* nv_arr, int* vidx,
                                                  float* accums, float* state0) {
  int b = blockIdx.x, lane = threadIdx.x;
  int s = 0;
  for (int i = lane; i < 512; i += 64) s += amask[b * 512 + i];
  for (int off = 32; off; off >>= 1) s += __shfl_down(s, off);
  if (lane == 0) lengths[b] = s;
  if (b == 0 && lane < 8) accums[lane] = 0.f;
  // zero h_a + h_b + c_buf: 3*65536 = 196608 floats
  for (int i = b * 64 + lane; i < 196608; i += 64 * 64) state0[i] = 0.f;
  if (lane == 0) {
    int nv = 0;
    for (int p = 0; p < 512; ++p) {
      if (tok_labels[b * 512 + p] >= 0) vidx[b * 512 + (nv++)] = p;
    }
    nv_arr[b] = nv;
  }
}

// ---------------------------------------------------------------------------
// One BiLSTM time step. 256 blocks x 256 thr. dir = wg&1, 4 hidden j per WG.
// thread: b = tid&63, slot = tid>>6 -> j. Stages x-chunk/h-chunk in LDS.
// Launched 512x sequentially: kernel boundaries provide the cross-block sync.
// ---------------------------------------------------------------------------
#define FMA4(hv, w0, w1, w2, w3)                                   \
  a0 += hv.x*w0.x + hv.y*w0.y + hv.z*w0.z + hv.w*w0.w;             \
  a1 += hv.x*w1.x + hv.y*w1.y + hv.z*w1.z + hv.w*w1.w;             \
  a2 += hv.x*w2.x + hv.y*w2.y + hv.z*w2.z + hv.w*w2.w;             \
  a3 += hv.x*w3.x + hv.y*w3.y + hv.z*w3.z + hv.w*w3.w;

__global__ void __launch_bounds__(256) lstm_step(StepParams P) {
  const int wg  = blockIdx.x;
  const int dir = wg & 1;
  const int jg  = wg >> 1;            // 0..127
  const int tid = threadIdx.x;
  const int b    = tid & 63;
  const int slot = tid >> 6;          // 0..3, wave-uniform
  const int j  = (jg << 2) + slot;    // hidden index 0..511
  const int t  = P.t;

  const float* Wih = dir ? P.Wih_r : P.Wih_f;
  const float* Whh = dir ? P.Whh_r : P.Whh_f;
  const float* bih = dir ? P.bih_r : P.bih_f;
  const float* bhh = dir ? P.bhh_r : P.bhh_f;

  __shared__ float buf[64][132];   // padded: float4 accesses conflict-free
  __shared__ int len_sh[64];
  if (tid < 64) len_sh[tid] = P.lengths[tid];

  float a0 = bih[j]        + bhh[j];
  float a1 = bih[512 + j]  + bhh[512 + j];
  float a2 = bih[1024 + j] + bhh[1024 + j];
  float a3 = bih[1536 + j] + bhh[1536 + j];

  const int len = P.lengths[b];
  const size_t sidx = (size_t)(dir * 64 + b) * 512 + j;
  const float c_old = P.c_buf[sidx];
  const float h_old = P.h_src[sidx];

  // -------- input projection: K=300 = 128+128+44
  for (int cidx = 0; cidx < 2; ++cidx) {
    const int kc = cidx << 7;
    __syncthreads();
    for (int i4 = tid; i4 < 2048; i4 += 256) {      // 64 rows x 32 float4
      int bb = i4 >> 5;
      int kq = (i4 & 31) << 2;
      int pos;
      if (dir) { pos = len_sh[bb] - 1 - t; if (pos < 0) pos = 0; }
      else pos = t;
      float4 v = *(const float4*)(P.x + ((size_t)bb * 512 + pos) * 300 + kc + kq);
      *(float4*)&buf[bb][kq] = v;
    }
    __syncthreads();
    const float* wr0 = Wih + (size_t)(j)        * 300 + kc;
    const float* wr1 = Wih + (size_t)(512 + j)  * 300 + kc;
    const float* wr2 = Wih + (size_t)(1024 + j) * 300 + kc;
    const float* wr3 = Wih + (size_t)(1536 + j) * 300 + kc;
    for (int k = 0; k < 128; k += 4) {
      float4 hv = *(const float4*)&buf[b][k];
      float4 w0 = *(const float4*)(wr0 + k);
      float4 w1 = *(const float4*)(wr1 + k);
      float4 w2 = *(const float4*)(wr2 + k);
      float4 w3 = *(const float4*)(wr3 + k);
      FMA4(hv, w0, w1, w2, w3)
    }
  }
  {
    const int kc = 256;                             // tail: 44 = 11 float4
    __syncthreads();
    for (int i4 = tid; i4 < 704; i4 += 256) {       // 64 rows x 11 float4
      int bb = i4 / 11;
      int kq = (i4 - bb * 11) << 2;
      int pos;
      if (dir) { pos = len_sh[bb] - 1 - t; if (pos < 0) pos = 0; }
      else pos = t;
      float4 v = *(const float4*)(P.x + ((size_t)bb * 512 + pos) * 300 + kc + kq);
      *(float4*)&buf[bb][kq] = v;
    }
    __syncthreads();
    const float* wr0 = Wih + (size_t)(j)        * 300 + kc;
    const float* wr1 = Wih + (size_t)(512 + j)  * 300 + kc;
    const float* wr2 = Wih + (size_t)(1024 + j) * 300 + kc;
    const float* wr3 = Wih + (size_t)(1536 + j) * 300 + kc;
    for (int k = 0; k < 44; k += 4) {
      float4 hv = *(const float4*)&buf[b][k];
      float4 w0 = *(const float4*)(wr0 + k);
      float4 w1 = *(const float4*)(wr1 + k);
      float4 w2 = *(const float4*)(wr2 + k);
      float4 w3 = *(const float4*)(wr3 + k);
      FMA4(hv, w0, w1, w2, w3)
    }
  }

  // -------- recurrent: K=512, 4 chunks of 128
  for (int cidx = 0; cidx < 4; ++cidx) {
    const int kc = cidx << 7;
    __syncthreads();
    for (int i4 = tid; i4 < 2048; i4 += 256) {
      int bb = i4 >> 5;
      int kq = (i4 & 31) << 2;
      float4 v = *(const float4*)(P.h_src + (size_t)(dir * 64 + bb) * 512 + kc + kq);
      *(float4*)&buf[bb][kq] = v;
    }
    __syncthreads();
    const float* wr0 = Whh + (size_t)(j)        * 512 + kc;
    const float* wr1 = Whh + (size_t)(512 + j)  * 512 + kc;
    const float* wr2 = Whh + (size_t)(1024 + j) * 512 + kc;
    const float* wr3 = Whh + (size_t)(1536 + j) * 512 + kc;
    for (int k = 0; k < 128; k += 4) {
      float4 hv = *(const float4*)&buf[b][k];
      float4 w0 = *(const float4*)(wr0 + k);
      float4 w1 = *(const float4*)(wr1 + k);
      float4 w2 = *(const float4*)(wr2 + k);
      float4 w3 = *(const float4*)(wr3 + k);
      FMA4(hv, w0, w1, w2, w3)
    }
  }

  // -------- state update
  const bool act = (t < len);
  float ig = 1.f / (1.f + expf(-a0));
  float fg = 1.f / (1.f + expf(-a1));
  float gg = tanhf(a2);
  float og = 1.f / (1.f + expf(-a3));
  float cn = fg * c_old + ig * gg;
  float hn = og * tanhf(cn);
  const float c_st = act ? cn : c_old;
  const float h_st = act ? hn : h_old;
  P.c_buf[sidx] = c_st;
  P.h_dst[sidx] = h_st;

  if (dir == 0) {
    P.outcat[((size_t)b * 512 + t) * 1024 + j] = act ? hn : 0.f;
  } else {
    if (act) P.outcat[((size_t)b * 512 + (len - 1 - t)) * 1024 + 512 + j] = hn;
    int sc = len + t;                       // zero-fill masked reverse slots
    if (sc < 512) P.outcat[((size_t)b * 512 + sc) * 1024 + 512 + j] = 0.f;
  }
  if (t == len - 1) P.h_red[(size_t)b * 1024 + dir * 512 + j] = hn;
}

// ---------------------------------------------------------------------------
// token logits: (B*S,1024) @ Wtok^T(9,1024) + btok. Wave-per-row, shfl reduce.
// ---------------------------------------------------------------------------
__global__ void __launch_bounds__(256) tok_kernel(const float* outcat, const float* Wtok,
                                                  const float* btok, float* out_tok) {
  __shared__ float wt[9 * 1024];
  __shared__ float bt[9];
  for (int i = threadIdx.x; i < 9216; i += 256) wt[i] = Wtok[i];
  if (threadIdx.x < 9) bt[threadIdx.x] = btok[threadIdx.x];
  __syncthreads();
  int wave = threadIdx.x >> 6, lane = threadIdx.x & 63;
  for (int r0 = 0; r0 < 32; ++r0) {
    int row = blockIdx.x * 128 + wave * 32 + r0;
    const float* src = outcat + (size_t)row * 1024;
    float f[16];
#pragma unroll
    for (int q = 0; q < 16; ++q) f[q] = src[lane + 64 * q];
#pragma unroll
    for (int n = 0; n < 9; ++n) {
      float s = 0.f;
#pragma unroll
      for (int q = 0; q < 16; ++q) s += f[q] * wt[n * 1024 + lane + 64 * q];
      for (int off = 32; off; off >>= 1) s += __shfl_down(s, off);
      if (lane == 0) out_tok[(size_t)row * 9 + n] = s + bt[n];
    }
  }
}

// ---------------------------------------------------------------------------
// seq head: tanh(h_red@Wd^T + bd) @ Wo^T + bo, log-softmax, weighted NLL
// ---------------------------------------------------------------------------
__global__ void __launch_bounds__(256) seq_kernel(const float* h_red, const float* Wd,
                                                  const float* bd, const float* Wo,
                                                  const float* bo, const float* scw,
                                                  const int* seq_labels, float* out_seq,
                                                  float* accums) {
  int bidx = blockIdx.x;
  __shared__ float xs[1024];
  __shared__ float ds[1024];
  __shared__ float red[8];
  for (int i = threadIdx.x; i < 1024; i += 256) xs[i] = h_red[(size_t)bidx * 1024 + i];
  __syncthreads();
  int wave = threadIdx.x >> 6, lane = threadIdx.x & 63;
  for (int oi = 0; oi < 256; ++oi) {
    int o = wave * 256 + oi;
    const float* wrow = Wd + (size_t)o * 1024;
    float s = 0.f;
#pragma unroll
    for (int q = 0; q < 16; ++q) s += xs[lane + 64 * q] * wrow[lane + 64 * q];
    for (int off = 32; off; off >>= 1) s += __shfl_down(s, off);
    if (lane == 0) ds[o] = tanhf(s + bd[o]);
  }
  __syncthreads();
  float p0 = 0.f, p1 = 0.f;
  for (int i = threadIdx.x; i < 1024; i += 256) {
    float dv = ds[i];
    p0 += dv * Wo[i];
    p1 += dv * Wo[1024 + i];
  }
  for (int off = 32; off; off >>= 1) { p0 += __shfl_down(p0, off); p1 += __shfl_down(p1, off); }
  if (lane == 0) { red[wave] = p0; red[4 + wave] = p1; }
  __syncthreads();
  if (threadIdx.x == 0) {
    float l0 = red[0] + red[1] + red[2] + red[3] + bo[0];
    float l1 = red[4] + red[5] + red[6] + red[7] + bo[1];
    out_seq[bidx * 2 + 0] = l0;
    out_seq[bidx * 2 + 1] = l1;
    float m = fmaxf(l0, l1);
    float lse = m + logf(expf(l0 - m) + expf(l1 - m));
    int lbl = seq_labels[bidx];
    float w = scw[lbl];
    float logp = (lbl ? l1 : l0) - lse;
    atomicAdd(&accums[2], -w * logp);
    atomicAdd(&accums[3], w);
  }
}

// ---------------------------------------------------------------------------
// CRF: one wave per batch. Lanes 0..8 hold alpha (forward) and viterbi score.
// tags output masked by VALIDITY mask (p < nv): reference's _crf_decode masks
// with the mask argument it receives, which is new_mask (labels>=0 compacted).
// ---------------------------------------------------------------------------
__global__ void __launch_bounds__(64) crf_kernel(const float* tok_logits, const int* tok_labels,
                                                 const int* vidx, const int* nv_arr,
                                                 const float* startv, const float* endv,
                                                 const float* trans, float* tags_out,
                                                 float* accums) {
  int b = blockIdx.x, lane = threadIdx.x;
  __shared__ int vsh[512];
  __shared__ int lsh[512];
  __shared__ unsigned char hist[512][16];
  __shared__ int tag_sh[512];
  const int nv = nv_arr[b];
  for (int p = lane; p < 512; p += 64) {
    int v = (p < nv) ? vidx[b * 512 + p] : 0;
    vsh[p] = v;
    lsh[p] = tok_labels[b * 512 + v];
  }
  __syncthreads();

  const int n = lane;
  const bool activeN = (n < 9);
  const int nc = activeN ? n : 0;          // clamped index: no OOB for lanes>=9
  float tcol[9];
#pragma unroll
  for (int mm = 0; mm < 9; ++mm) tcol[mm] = trans[mm * 9 + nc];

  const float* emb = tok_logits + (size_t)b * 512 * 9;
  float em0 = emb[(size_t)vsh[0] * 9 + nc];
  float alpha = startv[nc] + em0;
  if (!activeN) alpha = -1e30f;
  float vsc = alpha;
  int labprev = lsh[0];
  float num = __shfl(alpha, labprev);      // start[lab0] + em0[lab0]

  for (int p = 1; p < 512; ++p) {
    const bool m_p = (p < nv);
    float emn = m_p ? emb[(size_t)vsh[p] * 9 + nc] : 0.f;
    float mx = -1e30f, best = -1e30f;
    int arg = 0;
    float cand[9];
#pragma unroll
    for (int mm = 0; mm < 9; ++mm) {
      float am = __shfl(alpha, mm);
      float vm = __shfl(vsc, mm);
      float cm = am + tcol[mm];
      float vc = vm + tcol[mm];
      cand[mm] = cm;
      mx = fmaxf(mx, cm);
      if (vc > best) { best = vc; arg = mm; }     // first-max on ties
    }
    float s = 0.f;
#pragma unroll
    for (int mm = 0; mm < 9; ++mm) s += expf(cand[mm] - mx);
    float nxt = mx + logf(s) + emn;
    float nsc = best + emn;
    int h = n;
    if (m_p) {
      h = arg;
      if (activeN) { alpha = nxt; vsc = nsc; }
    }
    if (activeN) hist[p][n] = (unsigned char)h;
    if (m_p) {
      int lab = lsh[p];
      float e_lab = __shfl(emn, lab);
      num += trans[labprev * 9 + lab] + e_lab;
      labprev = lab;
    }
  }
  num += endv[labprev];

  float aend = activeN ? (alpha + endv[nc]) : -1e30f;
  float vend = activeN ? (vsc + endv[nc]) : -1e30f;
  float mx2 = -1e30f, best2 = -1e30f;
  int ltag = 0;
#pragma unroll
  for (int mm = 0; mm < 9; ++mm) {
    float am = __shfl(aend, mm);
    float vm = __shfl(vend, mm);
    mx2 = fmaxf(mx2, am);
    if (vm > best2) { best2 = vm; ltag = mm; }
  }
  float s2 = 0.f;
#pragma unroll
  for (int mm = 0; mm < 9; ++mm) { float am = __shfl(aend, mm); s2 += expf(am - mx2); }
  float den = mx2 + logf(s2);

  if (lane == 0) {
    atomicAdd(&accums[0], num - den);
    atomicAdd(&accums[1], (float)nv);
    int tg = ltag;
    for (int p = 511; p >= 1; --p) { tag_sh[p] = tg; tg = hist[p][tg]; }
    tag_sh[0] = tg;
  }
  __syncthreads();
  // reference: where(new_mask, tags, -1) -> validity mask
  for (int p = lane; p < 512; p += 64)
    tags_out[(size_t)b * 512 + p] = (p < nv) ? (float)tag_sh[p] : -1.0f;
}

__global__ void loss_kernel(const float* accums, float* out_loss) {
  if (threadIdx.x == 0 && blockIdx.x == 0)
    out_loss[0] = -(accums[0] / accums[1]) + accums[2] / accums[3];
}

// ---------------------------------------------------------------------------
extern "C" void kernel_launch(void* const* d_in, const int* in_sizes, int n_in,
                              void* d_out, int out_size, void* d_ws, size_t ws_size,
                              hipStream_t stream) {
  const float* x          = (const float*)d_in[0];
  const int*   amask      = (const int*)d_in[1];
  const int*   seq_labels = (const int*)d_in[2];
  const int*   tok_labels = (const int*)d_in[3];
  const float* scw        = (const float*)d_in[4];
  const float* Wih_f = (const float*)d_in[5];
  const float* Whh_f = (const float*)d_in[6];
  const float* bih_f = (const float*)d_in[7];
  const float* bhh_f = (const float*)d_in[8];
  const float* Wih_r = (const float*)d_in[9];
  const float* Whh_r = (const float*)d_in[10];
  const float* bih_r = (const float*)d_in[11];
  const float* bhh_r = (const float*)d_in[12];
  const float* Wtok  = (const float*)d_in[13];
  const float* btok  = (const float*)d_in[14];
  const float* Wd    = (const float*)d_in[15];
  const float* bd    = (const float*)d_in[16];
  const float* Wo    = (const float*)d_in[17];
  const float* bo    = (const float*)d_in[18];
  const float* crf_start = (const float*)d_in[19];
  const float* crf_end   = (const float*)d_in[20];
  const float* crf_trans = (const float*)d_in[21];

  float* ws = (float*)d_ws;
  float* h_a    = ws;                     // [2][64][512]
  float* h_b    = ws + 65536;             // [2][64][512]
  float* c_buf  = ws + 131072;            // [2][64][512]
  float* h_red  = ws + 196608;            // [64][1024]
  int*   lengths = (int*)(ws + 262144);   // [64]
  int*   nv_arr  = (int*)(ws + 262208);   // [64]
  int*   vidx    = (int*)(ws + 262272);   // [64][512]
  float* accums  = ws + 295040;           // [8]
  float* outcat  = ws + 295168;           // [64][512][1024] = 128 MiB

  float* out      = (float*)d_out;
  float* out_loss = out;
  float* out_tok  = out + 1;
  float* out_seq  = out + 294913;
  float* out_tags = out + 295041;

  prep_kernel<<<64, 64, 0, stream>>>(amask, tok_labels, lengths, nv_arr, vidx, accums, h_a);

  for (int t = 0; t < 512; ++t) {
    StepParams sp;
    sp.x = x;
    sp.Wih_f = Wih_f; sp.Whh_f = Whh_f; sp.bih_f = bih_f; sp.bhh_f = bhh_f;
    sp.Wih_r = Wih_r; sp.Whh_r = Whh_r; sp.bih_r = bih_r; sp.bhh_r = bhh_r;
    sp.h_src = (t & 1) ? h_b : h_a;
    sp.h_dst = (t & 1) ? h_a : h_b;
    sp.c_buf = c_buf; sp.outcat = outcat; sp.h_red = h_red;
    sp.lengths = lengths; sp.t = t;
    lstm_step<<<256, 256, 0, stream>>>(sp);
  }

  tok_kernel<<<256, 256, 0, stream>>>(outcat, Wtok, btok, out_tok);
  seq_kernel<<<64, 256, 0, stream>>>(h_red, Wd, bd, Wo, bo, scw, seq_labels, out_seq, accums);
  crf_kernel<<<64, 64, 0, stream>>>(out_tok, tok_labels, vidx, nv_arr,
                                    crf_start, crf_end, crf_trans, out_tags, accums);
  loss_kernel<<<1, 64, 0, stream>>>(accums, out_loss);
}

// Round 8
// 502945.850 us; speedup vs baseline: 1.0016x; 1.0016x over previous
//
#include <hip/hip_runtime.h>
#include <math.h>

// Problem constants: B=64, S=512, IN=300, H=512, NT=9, NC=2

struct StepParams {
  const float* x;
  const float* Wih_f; const float* Whh_f; const float* bih_f; const float* bhh_f;
  const float* Wih_r; const float* Whh_r; const float* bih_r; const float* bhh_r;
  const float* h_src; float* h_dst; float* c_buf; float* outcat; float* h_red;
  const float* xw;
  const int* lengths; int t;
};

// ---------------------------------------------------------------------------
// prep: lengths, CRF valid-index compaction, zero h_a/h_b/c/accums
// ---------------------------------------------------------------------------
__global__ void __launch_bounds__(64) prep_kernel(const int* amask, const int* tok_labels,
                                                  int* lengths, int* nv_arr, int* vidx,
                                                  float* accums, float* state0) {
  int b = blockIdx.x, lane = threadIdx.x;
  int s = 0;
  for (int i = lane; i < 512; i += 64) s += amask[b * 512 + i];
  for (int off = 32; off; off >>= 1) s += __shfl_down(s, off);
  if (lane == 0) lengths[b] = s;
  if (b == 0 && lane < 8) accums[lane] = 0.f;
  // zero h_a + h_b + c_buf: 3*65536 = 196608 floats
  for (int i = b * 64 + lane; i < 196608; i += 64 * 64) state0[i] = 0.f;
  if (lane == 0) {
    int nv = 0;
    for (int p = 0; p < 512; ++p) {
      if (tok_labels[b * 512 + p] >= 0) vidx[b * 512 + (nv++)] = p;
    }
    nv_arr[b] = nv;
  }
}

#define FMA4(hv, w0, w1, w2, w3)                                   \
  a0 += hv.x*w0.x + hv.y*w0.y + hv.z*w0.z + hv.w*w0.w;             \
  a1 += hv.x*w1.x + hv.y*w1.y + hv.z*w1.z + hv.w*w1.w;             \
  a2 += hv.x*w2.x + hv.y*w2.y + hv.z*w2.z + hv.w*w2.w;             \
  a3 += hv.x*w3.x + hv.y*w3.y + hv.z*w3.z + hv.w*w3.w;

// ---------------------------------------------------------------------------
// xw precompute: xw[dir][t][g*512+j][b] = bias[g,j] + x[b][pos(dir,b,t)] . Wih[g*512+j]
// Fully parallel (h-independent). Block = (dir, t, jg16): 16 j values.
// Same staging + accumulation order as the fused path (bit-identical x-dots).
// ---------------------------------------------------------------------------
__global__ void __launch_bounds__(256) xw_kernel(const float* x,
                                                 const float* Wih_f, const float* bih_f, const float* bhh_f,
                                                 const float* Wih_r, const float* bih_r, const float* bhh_r,
                                                 const int* lengths, float* xw) {
  const int bid  = blockIdx.x;          // 32768 = 2 * 512 * 32
  const int dir  = bid >> 14;
  const int rem  = bid & 16383;
  const int t    = rem >> 5;
  const int jg16 = rem & 31;
  const int tid  = threadIdx.x;
  const int b    = tid & 63;
  const int slot = tid >> 6;            // wave-uniform
  const int j0   = jg16 * 16 + slot * 4;

  const float* Wih = dir ? Wih_r : Wih_f;
  const float* bih = dir ? bih_r : bih_f;
  const float* bhh = dir ? bhh_r : bhh_f;

  __shared__ float buf[64][132];
  __shared__ int len_sh[64];
  if (tid < 64) len_sh[tid] = lengths[tid];

  float acc[4][4];
#pragma unroll
  for (int jj = 0; jj < 4; ++jj)
#pragma unroll
    for (int g = 0; g < 4; ++g)
      acc[jj][g] = bih[g * 512 + j0 + jj] + bhh[g * 512 + j0 + jj];

  // chunk 0/1: 128 wide; chunk 2: 44 wide
  for (int cidx = 0; cidx < 3; ++cidx) {
    const int kc   = cidx << 7;
    const int klen = (cidx == 2) ? 44 : 128;
    __syncthreads();
    if (cidx < 2) {
      for (int i4 = tid; i4 < 2048; i4 += 256) {
        int bb = i4 >> 5;
        int kq = (i4 & 31) << 2;
        int pos;
        if (dir) { pos = len_sh[bb] - 1 - t; if (pos < 0) pos = 0; }
        else pos = t;
        float4 v = *(const float4*)(x + ((size_t)bb * 512 + pos) * 300 + kc + kq);
        *(float4*)&buf[bb][kq] = v;
      }
    } else {
      for (int i4 = tid; i4 < 704; i4 += 256) {
        int bb = i4 / 11;
        int kq = (i4 - bb * 11) << 2;
        int pos;
        if (dir) { pos = len_sh[bb] - 1 - t; if (pos < 0) pos = 0; }
        else pos = t;
        float4 v = *(const float4*)(x + ((size_t)bb * 512 + pos) * 300 + kc + kq);
        *(float4*)&buf[bb][kq] = v;
      }
    }
    __syncthreads();
#pragma unroll
    for (int jj = 0; jj < 4; ++jj) {
      const int j = j0 + jj;
      const float* wr0 = Wih + (size_t)(j)        * 300 + kc;
      const float* wr1 = Wih + (size_t)(512 + j)  * 300 + kc;
      const float* wr2 = Wih + (size_t)(1024 + j) * 300 + kc;
      const float* wr3 = Wih + (size_t)(1536 + j) * 300 + kc;
      float a0 = acc[jj][0], a1 = acc[jj][1], a2 = acc[jj][2], a3 = acc[jj][3];
      for (int k = 0; k < klen; k += 4) {
        float4 hv = *(const float4*)&buf[b][k];
        float4 w0 = *(const float4*)(wr0 + k);
        float4 w1 = *(const float4*)(wr1 + k);
        float4 w2 = *(const float4*)(wr2 + k);
        float4 w3 = *(const float4*)(wr3 + k);
        FMA4(hv, w0, w1, w2, w3)
      }
      acc[jj][0] = a0; acc[jj][1] = a1; acc[jj][2] = a2; acc[jj][3] = a3;
    }
  }

  // write: xw[((dir*512+t)*2048 + g*512 + j)*64 + b] — lanes b coalesce
  float* base = xw + ((size_t)(dir * 512 + t) * 2048) * 64 + b;
#pragma unroll
  for (int jj = 0; jj < 4; ++jj)
#pragma unroll
    for (int g = 0; g < 4; ++g)
      base[(size_t)(g * 512 + j0 + jj) * 64] = acc[jj][g];
}

// ---------------------------------------------------------------------------
// One BiLSTM time step. 256 blocks x 256 thr. dir = wg&1, 4 hidden j per WG.
// USE_XW: gate pre-activations read from precomputed xw (bias folded).
// Fallback (!USE_XW): identical to the verified R7 kernel.
// ---------------------------------------------------------------------------
template <bool USE_XW>
__global__ void __launch_bounds__(256) lstm_step(StepParams P) {
  const int wg  = blockIdx.x;
  const int dir = wg & 1;
  const int jg  = wg >> 1;            // 0..127
  const int tid = threadIdx.x;
  const int b    = tid & 63;
  const int slot = tid >> 6;          // 0..3, wave-uniform
  const int j  = (jg << 2) + slot;    // hidden index 0..511
  const int t  = P.t;

  const float* Whh = dir ? P.Whh_r : P.Whh_f;

  __shared__ float buf[64][132];
  __shared__ int len_sh[64];
  if (tid < 64) len_sh[tid] = P.lengths[tid];

  float a0, a1, a2, a3;
  if constexpr (USE_XW) {
    const float* xwp = P.xw + ((size_t)(dir * 512 + t) * 2048) * 64 + b;
    a0 = xwp[(size_t)(j)        * 64];
    a1 = xwp[(size_t)(512 + j)  * 64];
    a2 = xwp[(size_t)(1024 + j) * 64];
    a3 = xwp[(size_t)(1536 + j) * 64];
  } else {
    const float* bih = dir ? P.bih_r : P.bih_f;
    const float* bhh = dir ? P.bhh_r : P.bhh_f;
    a0 = bih[j]        + bhh[j];
    a1 = bih[512 + j]  + bhh[512 + j];
    a2 = bih[1024 + j] + bhh[1024 + j];
    a3 = bih[1536 + j] + bhh[1536 + j];
  }

  const int len = P.lengths[b];
  const size_t sidx = (size_t)(dir * 64 + b) * 512 + j;
  const float c_old = P.c_buf[sidx];
  const float h_old = P.h_src[sidx];

  if constexpr (!USE_XW) {
    const float* Wih = dir ? P.Wih_r : P.Wih_f;
    for (int cidx = 0; cidx < 2; ++cidx) {
      const int kc = cidx << 7;
      __syncthreads();
      for (int i4 = tid; i4 < 2048; i4 += 256) {
        int bb = i4 >> 5;
        int kq = (i4 & 31) << 2;
        int pos;
        if (dir) { pos = len_sh[bb] - 1 - t; if (pos < 0) pos = 0; }
        else pos = t;
        float4 v = *(const float4*)(P.x + ((size_t)bb * 512 + pos) * 300 + kc + kq);
        *(float4*)&buf[bb][kq] = v;
      }
      __syncthreads();
      const float* wr0 = Wih + (size_t)(j)        * 300 + kc;
      const float* wr1 = Wih + (size_t)(512 + j)  * 300 + kc;
      const float* wr2 = Wih + (size_t)(1024 + j) * 300 + kc;
      const float* wr3 = Wih + (size_t)(1536 + j) * 300 + kc;
      for (int k = 0; k < 128; k += 4) {
        float4 hv = *(const float4*)&buf[b][k];
        float4 w0 = *(const float4*)(wr0 + k);
        float4 w1 = *(const float4*)(wr1 + k);
        float4 w2 = *(const float4*)(wr2 + k);
        float4 w3 = *(const float4*)(wr3 + k);
        FMA4(hv, w0, w1, w2, w3)
      }
    }
    {
      const int kc = 256;
      __syncthreads();
      for (int i4 = tid; i4 < 704; i4 += 256) {
        int bb = i4 / 11;
        int kq = (i4 - bb * 11) << 2;
        int pos;
        if (dir) { pos = len_sh[bb] - 1 - t; if (pos < 0) pos = 0; }
        else pos = t;
        float4 v = *(const float4*)(P.x + ((size_t)bb * 512 + pos) * 300 + kc + kq);
        *(float4*)&buf[bb][kq] = v;
      }
      __syncthreads();
      const float* Wih2 = Wih;
      const float* wr0 = Wih2 + (size_t)(j)        * 300 + kc;
      const float* wr1 = Wih2 + (size_t)(512 + j)  * 300 + kc;
      const float* wr2 = Wih2 + (size_t)(1024 + j) * 300 + kc;
      const float* wr3 = Wih2 + (size_t)(1536 + j) * 300 + kc;
      for (int k = 0; k < 44; k += 4) {
        float4 hv = *(const float4*)&buf[b][k];
        float4 w0 = *(const float4*)(wr0 + k);
        float4 w1 = *(const float4*)(wr1 + k);
        float4 w2 = *(const float4*)(wr2 + k);
        float4 w3 = *(const float4*)(wr3 + k);
        FMA4(hv, w0, w1, w2, w3)
      }
    }
  }

  // -------- recurrent: K=512, 4 chunks of 128
  for (int cidx = 0; cidx < 4; ++cidx) {
    const int kc = cidx << 7;
    __syncthreads();
    for (int i4 = tid; i4 < 2048; i4 += 256) {
      int bb = i4 >> 5;
      int kq = (i4 & 31) << 2;
      float4 v = *(const float4*)(P.h_src + (size_t)(dir * 64 + bb) * 512 + kc + kq);
      *(float4*)&buf[bb][kq] = v;
    }
    __syncthreads();
    const float* wr0 = Whh + (size_t)(j)        * 512 + kc;
    const float* wr1 = Whh + (size_t)(512 + j)  * 512 + kc;
    const float* wr2 = Whh + (size_t)(1024 + j) * 512 + kc;
    const float* wr3 = Whh + (size_t)(1536 + j) * 512 + kc;
    for (int k = 0; k < 128; k += 4) {
      float4 hv = *(const float4*)&buf[b][k];
      float4 w0 = *(const float4*)(wr0 + k);
      float4 w1 = *(const float4*)(wr1 + k);
      float4 w2 = *(const float4*)(wr2 + k);
      float4 w3 = *(const float4*)(wr3 + k);
      FMA4(hv, w0, w1, w2, w3)
    }
  }

  // -------- state update
  const bool act = (t < len);
  float ig = 1.f / (1.f + expf(-a0));
  float fg = 1.f / (1.f + expf(-a1));
  float gg = tanhf(a2);
  float og = 1.f / (1.f + expf(-a3));
  float cn = fg * c_old + ig * gg;
  float hn = og * tanhf(cn);
  const float c_st = act ? cn : c_old;
  const float h_st = act ? hn : h_old;
  P.c_buf[sidx] = c_st;
  P.h_dst[sidx] = h_st;

  if (dir == 0) {
    P.outcat[((size_t)b * 512 + t) * 1024 + j] = act ? hn : 0.f;
  } else {
    if (act) P.outcat[((size_t)b * 512 + (len - 1 - t)) * 1024 + 512 + j] = hn;
    int sc = len + t;
    if (sc < 512) P.outcat[((size_t)b * 512 + sc) * 1024 + 512 + j] = 0.f;
  }
  if (t == len - 1) P.h_red[(size_t)b * 1024 + dir * 512 + j] = hn;
}

// ---------------------------------------------------------------------------
// token logits: (B*S,1024) @ Wtok^T(9,1024) + btok. Wave-per-row, shfl reduce.
// ---------------------------------------------------------------------------
__global__ void __launch_bounds__(256) tok_kernel(const float* outcat, const float* Wtok,
                                                  const float* btok, float* out_tok) {
  __shared__ float wt[9 * 1024];
  __shared__ float bt[9];
  for (int i = threadIdx.x; i < 9216; i += 256) wt[i] = Wtok[i];
  if (threadIdx.x < 9) bt[threadIdx.x] = btok[threadIdx.x];
  __syncthreads();
  int wave = threadIdx.x >> 6, lane = threadIdx.x & 63;
  for (int r0 = 0; r0 < 32; ++r0) {
    int row = blockIdx.x * 128 + wave * 32 + r0;
    const float* src = outcat + (size_t)row * 1024;
    float f[16];
#pragma unroll
    for (int q = 0; q < 16; ++q) f[q] = src[lane + 64 * q];
#pragma unroll
    for (int n = 0; n < 9; ++n) {
      float s = 0.f;
#pragma unroll
      for (int q = 0; q < 16; ++q) s += f[q] * wt[n * 1024 + lane + 64 * q];
      for (int off = 32; off; off >>= 1) s += __shfl_down(s, off);
      if (lane == 0) out_tok[(size_t)row * 9 + n] = s + bt[n];
    }
  }
}

// ---------------------------------------------------------------------------
// seq head: tanh(h_red@Wd^T + bd) @ Wo^T + bo, log-softmax, weighted NLL
// ---------------------------------------------------------------------------
__global__ void __launch_bounds__(256) seq_kernel(const float* h_red, const float* Wd,
                                                  const float* bd, const float* Wo,
                                                  const float* bo, const float* scw,
                                                  const int* seq_labels, float* out_seq,
                                                  float* accums) {
  int bidx = blockIdx.x;
  __shared__ float xs[1024];
  __shared__ float ds[1024];
  __shared__ float red[8];
  for (int i = threadIdx.x; i < 1024; i += 256) xs[i] = h_red[(size_t)bidx * 1024 + i];
  __syncthreads();
  int wave = threadIdx.x >> 6, lane = threadIdx.x & 63;
  for (int oi = 0; oi < 256; ++oi) {
    int o = wave * 256 + oi;
    const float* wrow = Wd + (size_t)o * 1024;
    float s = 0.f;
#pragma unroll
    for (int q = 0; q < 16; ++q) s += xs[lane + 64 * q] * wrow[lane + 64 * q];
    for (int off = 32; off; off >>= 1) s += __shfl_down(s, off);
    if (lane == 0) ds[o] = tanhf(s + bd[o]);
  }
  __syncthreads();
  float p0 = 0.f, p1 = 0.f;
  for (int i = threadIdx.x; i < 1024; i += 256) {
    float dv = ds[i];
    p0 += dv * Wo[i];
    p1 += dv * Wo[1024 + i];
  }
  for (int off = 32; off; off >>= 1) { p0 += __shfl_down(p0, off); p1 += __shfl_down(p1, off); }
  if (lane == 0) { red[wave] = p0; red[4 + wave] = p1; }
  __syncthreads();
  if (threadIdx.x == 0) {
    float l0 = red[0] + red[1] + red[2] + red[3] + bo[0];
    float l1 = red[4] + red[5] + red[6] + red[7] + bo[1];
    out_seq[bidx * 2 + 0] = l0;
    out_seq[bidx * 2 + 1] = l1;
    float m = fmaxf(l0, l1);
    float lse = m + logf(expf(l0 - m) + expf(l1 - m));
    int lbl = seq_labels[bidx];
    float w = scw[lbl];
    float logp = (lbl ? l1 : l0) - lse;
    atomicAdd(&accums[2], -w * logp);
    atomicAdd(&accums[3], w);
  }
}

// ---------------------------------------------------------------------------
// CRF: one wave per batch. Lanes 0..8 hold alpha (forward) and viterbi score.
// ---------------------------------------------------------------------------
__global__ void __launch_bounds__(64) crf_kernel(const float* tok_logits, const int* tok_labels,
                                                 const int* vidx, const int* nv_arr,
                                                 const float* startv, const float* endv,
                                                 const float* trans, float* tags_out,
                                                 float* accums) {
  int b = blockIdx.x, lane = threadIdx.x;
  __shared__ int vsh[512];
  __shared__ int lsh[512];
  __shared__ unsigned char hist[512][16];
  __shared__ int tag_sh[512];
  const int nv = nv_arr[b];
  for (int p = lane; p < 512; p += 64) {
    int v = (p < nv) ? vidx[b * 512 + p] : 0;
    vsh[p] = v;
    lsh[p] = tok_labels[b * 512 + v];
  }
  __syncthreads();

  const int n = lane;
  const bool activeN = (n < 9);
  const int nc = activeN ? n : 0;
  float tcol[9];
#pragma unroll
  for (int mm = 0; mm < 9; ++mm) tcol[mm] = trans[mm * 9 + nc];

  const float* emb = tok_logits + (size_t)b * 512 * 9;
  float em0 = emb[(size_t)vsh[0] * 9 + nc];
  float alpha = startv[nc] + em0;
  if (!activeN) alpha = -1e30f;
  float vsc = alpha;
  int labprev = lsh[0];
  float num = __shfl(alpha, labprev);

  for (int p = 1; p < 512; ++p) {
    const bool m_p = (p < nv);
    float emn = m_p ? emb[(size_t)vsh[p] * 9 + nc] : 0.f;
    float mx = -1e30f, best = -1e30f;
    int arg = 0;
    float cand[9];
#pragma unroll
    for (int mm = 0; mm < 9; ++mm) {
      float am = __shfl(alpha, mm);
      float vm = __shfl(vsc, mm);
      float cm = am + tcol[mm];
      float vc = vm + tcol[mm];
      cand[mm] = cm;
      mx = fmaxf(mx, cm);
      if (vc > best) { best = vc; arg = mm; }
    }
    float s = 0.f;
#pragma unroll
    for (int mm = 0; mm < 9; ++mm) s += expf(cand[mm] - mx);
    float nxt = mx + logf(s) + emn;
    float nsc = best + emn;
    int h = n;
    if (m_p) {
      h = arg;
      if (activeN) { alpha = nxt; vsc = nsc; }
    }
    if (activeN) hist[p][n] = (unsigned char)h;
    if (m_p) {
      int lab = lsh[p];
      float e_lab = __shfl(emn, lab);
      num += trans[labprev * 9 + lab] + e_lab;
      labprev = lab;
    }
  }
  num += endv[labprev];

  float aend = activeN ? (alpha + endv[nc]) : -1e30f;
  float vend = activeN ? (vsc + endv[nc]) : -1e30f;
  float mx2 = -1e30f, best2 = -1e30f;
  int ltag = 0;
#pragma unroll
  for (int mm = 0; mm < 9; ++mm) {
    float am = __shfl(aend, mm);
    float vm = __shfl(vend, mm);
    mx2 = fmaxf(mx2, am);
    if (vm > best2) { best2 = vm; ltag = mm; }
  }
  float s2 = 0.f;
#pragma unroll
  for (int mm = 0; mm < 9; ++mm) { float am = __shfl(aend, mm); s2 += expf(am - mx2); }
  float den = mx2 + logf(s2);

  if (lane == 0) {
    atomicAdd(&accums[0], num - den);
    atomicAdd(&accums[1], (float)nv);
    int tg = ltag;
    for (int p = 511; p >= 1; --p) { tag_sh[p] = tg; tg = hist[p][tg]; }
    tag_sh[0] = tg;
  }
  __syncthreads();
  for (int p = lane; p < 512; p += 64)
    tags_out[(size_t)b * 512 + p] = (p < nv) ? (float)tag_sh[p] : -1.0f;
}

__global__ void loss_kernel(const float* accums, float* out_loss) {
  if (threadIdx.x == 0 && blockIdx.x == 0)
    out_loss[0] = -(accums[0] / accums[1]) + accums[2] / accums[3];
}

// ---------------------------------------------------------------------------
extern "C" void kernel_launch(void* const* d_in, const int* in_sizes, int n_in,
                              void* d_out, int out_size, void* d_ws, size_t ws_size,
                              hipStream_t stream) {
  const float* x          = (const float*)d_in[0];
  const int*   amask      = (const int*)d_in[1];
  const int*   seq_labels = (const int*)d_in[2];
  const int*   tok_labels = (const int*)d_in[3];
  const float* scw        = (const float*)d_in[4];
  const float* Wih_f = (const float*)d_in[5];
  const float* Whh_f = (const float*)d_in[6];
  const float* bih_f = (const float*)d_in[7];
  const float* bhh_f = (const float*)d_in[8];
  const float* Wih_r = (const float*)d_in[9];
  const float* Whh_r = (const float*)d_in[10];
  const float* bih_r = (const float*)d_in[11];
  const float* bhh_r = (const float*)d_in[12];
  const float* Wtok  = (const float*)d_in[13];
  const float* btok  = (const float*)d_in[14];
  const float* Wd    = (const float*)d_in[15];
  const float* bd    = (const float*)d_in[16];
  const float* Wo    = (const float*)d_in[17];
  const float* bo    = (const float*)d_in[18];
  const float* crf_start = (const float*)d_in[19];
  const float* crf_end   = (const float*)d_in[20];
  const float* crf_trans = (const float*)d_in[21];

  float* ws = (float*)d_ws;
  float* h_a    = ws;                     // [2][64][512]
  float* h_b    = ws + 65536;             // [2][64][512]
  float* c_buf  = ws + 131072;            // [2][64][512]
  float* h_red  = ws + 196608;            // [64][1024]
  int*   lengths = (int*)(ws + 262144);   // [64]
  int*   nv_arr  = (int*)(ws + 262208);   // [64]
  int*   vidx    = (int*)(ws + 262272);   // [64][512]
  float* accums  = ws + 295040;           // [8]
  float* outcat  = ws + 295168;           // [64][512][1024] = 128 MiB
  float* xw      = ws + 33849600;         // [2][512][2048][64] = 512 MiB (optional)

  const bool use_xw = (ws_size >= 672269312ull);

  float* out      = (float*)d_out;
  float* out_loss = out;
  float* out_tok  = out + 1;
  float* out_seq  = out + 294913;
  float* out_tags = out + 295041;

  prep_kernel<<<64, 64, 0, stream>>>(amask, tok_labels, lengths, nv_arr, vidx, accums, h_a);

  if (use_xw) {
    xw_kernel<<<32768, 256, 0, stream>>>(x, Wih_f, bih_f, bhh_f, Wih_r, bih_r, bhh_r,
                                         lengths, xw);
  }

  for (int t = 0; t < 512; ++t) {
    StepParams sp;
    sp.x = x;
    sp.Wih_f = Wih_f; sp.Whh_f = Whh_f; sp.bih_f = bih_f; sp.bhh_f = bhh_f;
    sp.Wih_r = Wih_r; sp.Whh_r = Whh_r; sp.bih_r = bih_r; sp.bhh_r = bhh_r;
    sp.h_src = (t & 1) ? h_b : h_a;
    sp.h_dst = (t & 1) ? h_a : h_b;
    sp.c_buf = c_buf; sp.outcat = outcat; sp.h_red = h_red;
    sp.xw = xw;
    sp.lengths = lengths; sp.t = t;
    if (use_xw) lstm_step<true><<<256, 256, 0, stream>>>(sp);
    else        lstm_step<false><<<256, 256, 0, stream>>>(sp);
  }

  tok_kernel<<<256, 256, 0, stream>>>(outcat, Wtok, btok, out_tok);
  seq_kernel<<<64, 256, 0, stream>>>(h_red, Wd, bd, Wo, bo, scw, seq_labels, out_seq, accums);
  crf_kernel<<<64, 64, 0, stream>>>(out_tok, tok_labels, vidx, nv_arr,
                                    crf_start, crf_end, crf_trans, out_tags, accums);
  loss_kernel<<<1, 64, 0, stream>>>(accums, out_loss);
}